// Round 2
// baseline (431.829 us; speedup 1.0000x reference)
//
#include <hip/hip_runtime.h>

typedef __attribute__((ext_vector_type(8))) short bf16x8;
typedef __attribute__((ext_vector_type(4))) float f32x4;

#define HH 8
#define DD 32
#define NB 512
#define BS 128
#define LKB 40    // Kb row stride (shorts): 32 + 8 pad
#define LVT 136   // Vt row stride (shorts): 128 + 8 pad
#define LPS 136   // P slab row stride (shorts)

__device__ __forceinline__ unsigned int f2bf(float f) {
    unsigned int u = __float_as_uint(f);
    u += 0x7fffu + ((u >> 16) & 1u);   // RNE
    return u >> 16;
}
__device__ __forceinline__ unsigned int pk2(float a, float b) {
    return f2bf(a) | (f2bf(b) << 16);
}

union U8 { uint4 u; bf16x8 v; };

__global__ __launch_bounds__(256, 4) void battn_kernel(
    const float* __restrict__ Qg, const float* __restrict__ Kg,
    const float* __restrict__ Vg, const int* __restrict__ SB,
    float* __restrict__ Og)
{
    __shared__ unsigned short Kb[BS * LKB];       // 10.0 KB  K bf16 [key][d]
    __shared__ unsigned short Vt[DD * LVT];       //  8.5 KB  V bf16 [d][key]
    __shared__ unsigned short Ps[4 * 16 * LPS];   // 17.0 KB  per-wave 16-query P slab
    // total 35.5 KB -> 4 blocks/CU

    const int bid = blockIdx.x;
    const int h = bid & 7;
    const int n = (bid >> 3) & (NB - 1);
    const int b = bid >> 12;
    const int tid = threadIdx.x;
    const int base = ((b * 65536 + n * BS) * HH + h) * DD;

    const int lane = tid & 63;
    const int w = tid >> 6;        // wave id: owns queries [w*32, w*32+32)
    const int l15 = lane & 15;
    const int quad = lane >> 4;
    const int q0row = w * 32;

    // ---- issue ALL global loads up front ----
    // Q: each lane loads its own B-fragment rows directly (no LDS round trip)
    const float* qp0 = Qg + base + (q0row + l15) * (HH * DD) + quad * 8;
    const float* qp1 = qp0 + 16 * (HH * DD);
    float4 qa0 = ((const float4*)qp0)[0], qb0 = ((const float4*)qp0)[1];
    float4 qa1 = ((const float4*)qp1)[0], qb1 = ((const float4*)qp1)[1];

    const int tok = tid >> 1, halfk = tid & 1;
    const float4* kv = (const float4*)(Kg + base + tok * (HH * DD) + halfk * 16);
    float4 c0 = kv[0], c1 = kv[1], c2 = kv[2], c3 = kv[3];

    const int vtok = tid & 127, vd0 = (tid >> 7) * 16;
    const float4* vvp = (const float4*)(Vg + base + vtok * (HH * DD) + vd0);
    float4 v0 = vvp[0], v1 = vvp[1], v2 = vvp[2], v3 = vvp[3];

    const int sb = (b * NB + n) * 2;
    const int st = SB[sb], en = SB[sb + 1];
    const int kbase = n * BS;

    // ---- stage K (bf16) ----
    uint4* kd = (uint4*)(Kb + tok * LKB + halfk * 16);
    kd[0] = make_uint4(pk2(c0.x,c0.y), pk2(c0.z,c0.w), pk2(c1.x,c1.y), pk2(c1.z,c1.w));
    kd[1] = make_uint4(pk2(c2.x,c2.y), pk2(c2.z,c2.w), pk2(c3.x,c3.y), pk2(c3.z,c3.w));

    // ---- stage V transposed (bf16) ----
    {
        float vf[16] = {v0.x,v0.y,v0.z,v0.w, v1.x,v1.y,v1.z,v1.w,
                        v2.x,v2.y,v2.z,v2.w, v3.x,v3.y,v3.z,v3.w};
        #pragma unroll
        for (int j = 0; j < 16; ++j)
            Vt[(vd0 + j) * LVT + vtok] = (unsigned short)f2bf(vf[j]);
    }

    // ---- build Q fragments, scale * log2(e) folded ----
    const float cs = 0.17677669529663687f * 1.4426950408889634f;
    U8 tq0, tq1;
    tq0.u = make_uint4(pk2(qa0.x*cs,qa0.y*cs), pk2(qa0.z*cs,qa0.w*cs),
                       pk2(qb0.x*cs,qb0.y*cs), pk2(qb0.z*cs,qb0.w*cs));
    tq1.u = make_uint4(pk2(qa1.x*cs,qa1.y*cs), pk2(qa1.z*cs,qa1.w*cs),
                       pk2(qb1.x*cs,qb1.y*cs), pk2(qb1.z*cs,qb1.w*cs));
    bf16x8 qf0 = tq0.v, qf1 = tq1.v;

    __syncthreads();   // the ONLY barrier

    // ---- S^T = K · Q^T : A = K tile (M=key), B = Q (N=query), one MFMA = full D=32 ----
    const f32x4 z = {0.f, 0.f, 0.f, 0.f};
    f32x4 acc0[8], acc1[8];
    #pragma unroll
    for (int kt = 0; kt < 8; ++kt) {
        bf16x8 kf = *(const bf16x8*)(Kb + (kt * 16 + l15) * LKB + quad * 8);
        acc0[kt] = __builtin_amdgcn_mfma_f32_16x16x32_bf16(kf, qf0, z, 0, 0, 0);
        acc1[kt] = __builtin_amdgcn_mfma_f32_16x16x32_bf16(kf, qf1, z, 0, 0, 0);
    }

    const bool full = (st <= kbase) && (en >= kbase + BS);
    unsigned short* myP = Ps + (w * 16 + l15) * LPS;

    // ================= pass 0: queries q0row .. q0row+15 =================
    float s0 = 0.f;
    if (full) {
        #pragma unroll
        for (int kt = 0; kt < 8; ++kt) {
            float e0 = __builtin_amdgcn_exp2f(acc0[kt][0]);
            float e1 = __builtin_amdgcn_exp2f(acc0[kt][1]);
            float e2 = __builtin_amdgcn_exp2f(acc0[kt][2]);
            float e3 = __builtin_amdgcn_exp2f(acc0[kt][3]);
            s0 += (e0 + e1) + (e2 + e3);
            *(uint2*)(myP + kt * 16 + quad * 4) = make_uint2(pk2(e0, e1), pk2(e2, e3));
        }
    } else {
        #pragma unroll
        for (int kt = 0; kt < 8; ++kt) {
            const int k0 = kbase + kt * 16 + quad * 4;
            float e0 = (k0+0 >= st && k0+0 < en) ? __builtin_amdgcn_exp2f(acc0[kt][0]) : 0.f;
            float e1 = (k0+1 >= st && k0+1 < en) ? __builtin_amdgcn_exp2f(acc0[kt][1]) : 0.f;
            float e2 = (k0+2 >= st && k0+2 < en) ? __builtin_amdgcn_exp2f(acc0[kt][2]) : 0.f;
            float e3 = (k0+3 >= st && k0+3 < en) ? __builtin_amdgcn_exp2f(acc0[kt][3]) : 0.f;
            s0 += (e0 + e1) + (e2 + e3);
            *(uint2*)(myP + kt * 16 + quad * 4) = make_uint2(pk2(e0, e1), pk2(e2, e3));
        }
    }
    s0 += __shfl_xor(s0, 16);
    s0 += __shfl_xor(s0, 32);

    f32x4 oA0 = z, oB0 = z;
    #pragma unroll
    for (int kc = 0; kc < 4; ++kc) {
        const int ko = kc * 32 + quad * 8;
        bf16x8 pf  = *(const bf16x8*)(myP + ko);
        bf16x8 vv0 = *(const bf16x8*)(Vt + l15 * LVT + ko);
        bf16x8 vv1 = *(const bf16x8*)(Vt + (16 + l15) * LVT + ko);
        oA0 = __builtin_amdgcn_mfma_f32_16x16x32_bf16(pf, vv0, oA0, 0, 0, 0);
        oB0 = __builtin_amdgcn_mfma_f32_16x16x32_bf16(pf, vv1, oB0, 0, 0, 0);
    }

    // ================= pass 1: queries q0row+16 .. q0row+31 =================
    // (same slab rows; within-wave DS ordering makes WAR safe, no barrier)
    float s1 = 0.f;
    if (full) {
        #pragma unroll
        for (int kt = 0; kt < 8; ++kt) {
            float e0 = __builtin_amdgcn_exp2f(acc1[kt][0]);
            float e1 = __builtin_amdgcn_exp2f(acc1[kt][1]);
            float e2 = __builtin_amdgcn_exp2f(acc1[kt][2]);
            float e3 = __builtin_amdgcn_exp2f(acc1[kt][3]);
            s1 += (e0 + e1) + (e2 + e3);
            *(uint2*)(myP + kt * 16 + quad * 4) = make_uint2(pk2(e0, e1), pk2(e2, e3));
        }
    } else {
        #pragma unroll
        for (int kt = 0; kt < 8; ++kt) {
            const int k0 = kbase + kt * 16 + quad * 4;
            float e0 = (k0+0 >= st && k0+0 < en) ? __builtin_amdgcn_exp2f(acc1[kt][0]) : 0.f;
            float e1 = (k0+1 >= st && k0+1 < en) ? __builtin_amdgcn_exp2f(acc1[kt][1]) : 0.f;
            float e2 = (k0+2 >= st && k0+2 < en) ? __builtin_amdgcn_exp2f(acc1[kt][2]) : 0.f;
            float e3 = (k0+3 >= st && k0+3 < en) ? __builtin_amdgcn_exp2f(acc1[kt][3]) : 0.f;
            s1 += (e0 + e1) + (e2 + e3);
            *(uint2*)(myP + kt * 16 + quad * 4) = make_uint2(pk2(e0, e1), pk2(e2, e3));
        }
    }
    s1 += __shfl_xor(s1, 16);
    s1 += __shfl_xor(s1, 32);

    f32x4 oA1 = z, oB1 = z;
    #pragma unroll
    for (int kc = 0; kc < 4; ++kc) {
        const int ko = kc * 32 + quad * 8;
        bf16x8 pf  = *(const bf16x8*)(myP + ko);
        bf16x8 vv0 = *(const bf16x8*)(Vt + l15 * LVT + ko);
        bf16x8 vv1 = *(const bf16x8*)(Vt + (16 + l15) * LVT + ko);
        oA1 = __builtin_amdgcn_mfma_f32_16x16x32_bf16(pf, vv0, oA1, 0, 0, 0);
        oB1 = __builtin_amdgcn_mfma_f32_16x16x32_bf16(pf, vv1, oB1, 0, 0, 0);
    }

    // ---- epilogue: normalize (1/sum via shfl), gate invalid queries, store ----
    const float inv0 = __builtin_amdgcn_rcpf(s0);
    const float inv1 = __builtin_amdgcn_rcpf(s1);
    #pragma unroll
    for (int mt = 0; mt < 2; ++mt) {
        #pragma unroll
        for (int r = 0; r < 4; ++r) {
            const int q = q0row + mt * 16 + quad * 4 + r;
            const int ap = kbase + q;
            float iv = __shfl(mt ? inv1 : inv0, quad * 4 + r);
            if (!(full || (ap >= st && ap < en))) iv = 0.f;
            const int go = base + q * (HH * DD);
            const f32x4& tA = mt ? oA1 : oA0;
            const f32x4& tB = mt ? oB1 : oB0;
            Og[go + l15] = tA[r] * iv;
            Og[go + 16 + l15] = tB[r] * iv;
        }
    }
}

extern "C" void kernel_launch(void* const* d_in, const int* in_sizes, int n_in,
                              void* d_out, int out_size, void* d_ws, size_t ws_size,
                              hipStream_t stream) {
    const float* Q = (const float*)d_in[0];
    const float* K = (const float*)d_in[1];
    const float* V = (const float*)d_in[2];
    const int* SB  = (const int*)d_in[3];
    float* O = (float*)d_out;
    battn_kernel<<<dim3(8192), dim3(256), 0, stream>>>(Q, K, V, SB, O);
}